// Round 8
// baseline (80.945 us; speedup 1.0000x reference)
//
#include <hip/hip_runtime.h>
#include <math.h>

#define ALPHA 0.2f

constexpr int CN0 = 512, CN1 = 2048, CN2 = 8192, CK = 33;
constexpr int CIN = 256, CHID = 128, CNH = 8;

using u16    = unsigned short;
using f32x4  = __attribute__((ext_vector_type(4))) float;
using bf16x8 = __attribute__((ext_vector_type(8))) short;
using short8 = __attribute__((ext_vector_type(8))) short;

__device__ __forceinline__ u16 f2bf(float f) {
    unsigned u = __float_as_uint(f);
    u += 0x7fff + ((u >> 16) & 1);   // RNE
    return (u16)(u >> 16);
}
__device__ __forceinline__ float bf2f(u16 h) {
    return __uint_as_float(((unsigned)h) << 16);
}

#define GLD16(g, l)                                                        \
    __builtin_amdgcn_global_load_lds(                                      \
        (const __attribute__((address_space(1))) void*)(g),                \
        (__attribute__((address_space(3))) void*)(l), 16, 0, 0)

// ---------------------------------------------------------------------------
// prep: feats-convert + W1/W2 transpose-convert + h2 zero-init.
// blocks [0,2048): feats; [2048,2304): W1 T; [2304,2432): W2 T;
// [2432,2560): h2 = 0 (for gemm2's atomic accumulation)
// ---------------------------------------------------------------------------
__global__ __launch_bounds__(256) void prep_k(const float* __restrict__ feats,
                                              u16* __restrict__ fb,
                                              const float* __restrict__ W1,
                                              u16* __restrict__ w1t,
                                              const float* __restrict__ W2,
                                              u16* __restrict__ w2t,
                                              float* __restrict__ h2) {
    __shared__ float t[32][33];
    int b = blockIdx.x;
    if (b < 2048) {
        const int i = (b * 256 + threadIdx.x) * 4;
        const float4 v = *reinterpret_cast<const float4*>(feats + i);
        *reinterpret_cast<ushort4*>(fb + i) =
            make_ushort4(f2bf(v.x), f2bf(v.y), f2bf(v.z), f2bf(v.w));
        return;
    }
    if (b >= 2432) {  // zero h2: 128 blocks x 256 thr x 8 f32 = 262144
        const int i = ((b - 2432) * 256 + threadIdx.x) * 8;
        const float4 z = make_float4(0.f, 0.f, 0.f, 0.f);
        *reinterpret_cast<float4*>(h2 + i)     = z;
        *reinterpret_cast<float4*>(h2 + i + 4) = z;
        return;
    }
    b -= 2048;
    const float* ip;
    u16* op;
    int R, C, r0, c0;
    if (b < 256) {  // W1 head h
        const int h = b >> 5, w = b & 31;
        ip = W1 + (size_t)h * CIN * CHID;
        op = w1t + (size_t)h * CIN * CHID;
        R = CIN; C = CHID; r0 = (w >> 2) * 32; c0 = (w & 3) * 32;
    } else {        // W2
        b -= 256;
        ip = W2; op = w2t;
        R = CNH * CHID; C = CHID; r0 = (b >> 2) * 32; c0 = (b & 3) * 32;
    }
    const int tx = threadIdx.x & 31, ty = threadIdx.x >> 5;
#pragma unroll
    for (int i = 0; i < 4; ++i)
        t[ty + 8 * i][tx] = ip[(size_t)(r0 + ty + 8 * i) * C + c0 + tx];
    __syncthreads();
#pragma unroll
    for (int i = 0; i < 4; ++i)
        op[(size_t)(c0 + ty + 8 * i) * R + r0 + tx] = f2bf(t[tx][ty + 8 * i]);
}

// ---------------------------------------------------------------------------
// bf16 MFMA GEMM, 64x128 tile, BK=32, 4 waves, 2-phase double-buffered LDS.
// Grid: blockIdx.x = COL tile (fastest -> 8 consecutive blocks share one
// A-tile across XCDs, L3 serves re-reads), blockIdx.y = ROW tile,
// blockIdx.z = K-split.
// BF16OUT: C staged through LDS -> coalesced dwordx4 stores.
// else:    atomicAdd f32 into Cf (split-K accumulation, h2 pre-zeroed).
// SCORES: fused per-row dual dot with av (col tile == one head).
// ---------------------------------------------------------------------------
template <int KSTEPS, bool BF16OUT, bool SCORES>
__global__ __launch_bounds__(256) void gemm_mfma(const u16* __restrict__ A, int lda,
                                                 const u16* __restrict__ Bt, int ldb,
                                                 u16* __restrict__ Cb,
                                                 float* __restrict__ Cf, int ldc,
                                                 const float* __restrict__ av,
                                                 float* __restrict__ s1o,
                                                 float* __restrict__ s2o,
                                                 int snodes) {
    // smem: 2 x (4KB A-buf + 8KB B-buf) = 24KB; bf16 C tile (64x136x2=17.4KB)
    // aliases it after the K-loop's final barrier.
    __shared__ __attribute__((aligned(16))) char smem[24576];

    const int tid  = threadIdx.x;
    const int lane = tid & 63;
    const int wave = tid >> 6;
    const int row0 = blockIdx.y * 64;
    const int col0 = blockIdx.x * 128;
    const int kbase = blockIdx.z * (KSTEPS * 32);
    const int wr = (wave >> 1) * 32;   // 0 / 32
    const int wc = (wave & 1) * 64;    // 0 / 64

    f32x4 acc[2][4];
#pragma unroll
    for (int m = 0; m < 2; ++m)
#pragma unroll
        for (int n = 0; n < 4; ++n) acc[m][n] = (f32x4){0.f, 0.f, 0.f, 0.f};

    // staging: swizzled global source chunk so fragment ds_read_b128 is ~free
    const int r0c = tid >> 2;          // 0..63
    const int cs0 = tid & 3;
    const int c0  = (cs0 - (r0c >> 1)) & 3;
    const int r1c = r0c + 64;

    const u16* ga0 = A + (size_t)(row0 + r0c) * lda + kbase + c0 * 8;
    const u16* gb0 = Bt + (size_t)(col0 + r0c) * ldb + kbase + c0 * 8;
    const u16* gb1 = Bt + (size_t)(col0 + r1c) * ldb + kbase + c0 * 8;

    auto STAGE = [&](int s) {
        const int k0 = s * 32;
        char* base = smem + (s & 1) * 12288;
        u16* as = (u16*)base + wave * 512;
        u16* bs = (u16*)(base + 4096) + wave * 512;
        GLD16(ga0 + k0, as);
        GLD16(gb0 + k0, bs);
        GLD16(gb1 + k0, bs + 2048);
    };

    STAGE(0);
    __syncthreads();

    for (int s = 0; s < KSTEPS; ++s) {
        if (s + 1 < KSTEPS) STAGE(s + 1);

        const u16* Acur = (const u16*)(smem + (s & 1) * 12288);
        const u16* Bcur = Acur + 2048;

        bf16x8 af[2], bfr[4];
#pragma unroll
        for (int m = 0; m < 2; ++m) {
            const int rt = wr + m * 16 + (lane & 15);
            const int cs = ((lane >> 4) + (rt >> 1)) & 3;
            af[m] = *reinterpret_cast<const bf16x8*>(Acur + rt * 32 + cs * 8);
        }
#pragma unroll
        for (int n = 0; n < 4; ++n) {
            const int rt2 = wc + n * 16 + (lane & 15);
            const int cs2 = ((lane >> 4) + (rt2 >> 1)) & 3;
            bfr[n] = *reinterpret_cast<const bf16x8*>(Bcur + rt2 * 32 + cs2 * 8);
        }
#pragma unroll
        for (int m = 0; m < 2; ++m)
#pragma unroll
            for (int n = 0; n < 4; ++n)
                acc[m][n] = __builtin_amdgcn_mfma_f32_16x16x32_bf16(
                    af[m], bfr[n], acc[m][n], 0, 0, 0);

        __syncthreads();
    }

    // C/D layout: col = lane&15, row = (lane>>4)*4 + q   [m89-verified]
    if constexpr (BF16OUT) {
        u16* Cs = (u16*)smem;   // aliases A/B buffers (dead after last barrier)
#pragma unroll
        for (int m = 0; m < 2; ++m) {
            const int rr = wr + m * 16 + (lane >> 4) * 4;
#pragma unroll
            for (int n = 0; n < 4; ++n) {
                const int cc = wc + n * 16 + (lane & 15);
#pragma unroll
                for (int q = 0; q < 4; ++q)
                    Cs[(rr + q) * 136 + cc] = f2bf(acc[m][n][q]);
            }
        }
        __syncthreads();
#pragma unroll
        for (int i = 0; i < 4; ++i) {
            const int cid = i * 256 + tid;       // 0..1023
            const int r  = cid >> 4;             // 0..63
            const int kc = cid & 15;
            const int4 v = *reinterpret_cast<const int4*>(&Cs[r * 136 + kc * 8]);
            *reinterpret_cast<int4*>(&Cb[(long)(row0 + r) * ldc + col0 + kc * 8]) = v;
        }
    } else {
        // split-K accumulation via device-scope f32 atomics (h2 pre-zeroed)
#pragma unroll
        for (int m = 0; m < 2; ++m) {
            const int rr = row0 + wr + m * 16 + (lane >> 4) * 4;
#pragma unroll
            for (int n = 0; n < 4; ++n) {
                const int cc = col0 + wc + n * 16 + (lane & 15);
#pragma unroll
                for (int q = 0; q < 4; ++q)
                    atomicAdd(&Cf[(long)(rr + q) * ldc + cc], acc[m][n][q]);
            }
        }
    }

    if constexpr (SCORES) {
        __shared__ float sred1[2][64];
        __shared__ float sred2[2][64];
        const int head = blockIdx.x;
        float av1[4], av2[4];
#pragma unroll
        for (int n = 0; n < 4; ++n) {
            const int c = wc + n * 16 + (lane & 15);
            av1[n] = av[head * 2 * CHID + c];
            av2[n] = av[head * 2 * CHID + CHID + c];
        }
        float p1[2][4], p2[2][4];
#pragma unroll
        for (int m = 0; m < 2; ++m)
#pragma unroll
            for (int q = 0; q < 4; ++q) {
                float t1 = 0.f, t2 = 0.f;
#pragma unroll
                for (int n = 0; n < 4; ++n) {
                    t1 = fmaf(acc[m][n][q], av1[n], t1);
                    t2 = fmaf(acc[m][n][q], av2[n], t2);
                }
#pragma unroll
                for (int mk = 1; mk < 16; mk <<= 1) {
                    t1 += __shfl_xor(t1, mk);
                    t2 += __shfl_xor(t2, mk);
                }
                p1[m][q] = t1;
                p2[m][q] = t2;
            }
        if ((lane & 15) == 0) {
            const int g = lane >> 4;
#pragma unroll
            for (int m = 0; m < 2; ++m)
#pragma unroll
                for (int q = 0; q < 4; ++q) {
                    sred1[wave & 1][wr + m * 16 + g * 4 + q] = p1[m][q];
                    sred2[wave & 1][wr + m * 16 + g * 4 + q] = p2[m][q];
                }
        }
        __syncthreads();
        if (tid < 64) {
            s1o[head * snodes + row0 + tid] = sred1[0][tid] + sred1[1][tid];
            s2o[head * snodes + row0 + tid] = sred2[0][tid] + sred2[1][tid];
        }
    }
}

// ---------------------------------------------------------------------------
// layer-1 softmax + aggregate + ELU.  One 128-thread block per target.
// ---------------------------------------------------------------------------
__global__ __launch_bounds__(128) void agg1_k(const float* __restrict__ s1,
                                              const float* __restrict__ s2,
                                              const int* __restrict__ src,
                                              const int* __restrict__ dst,
                                              const u16* __restrict__ hm,
                                              u16* __restrict__ xout) {
    __shared__ float wgt[CNH][CK];
    __shared__ int dsts[CK];

    const int t    = blockIdx.x;
    const int tid  = threadIdx.x;
    const int wv   = tid >> 6;
    const int lane = tid & 63;

    int sv = 0, dv = 0;
    if (lane < CK) {
        sv = src[t * CK + lane];
        dv = dst[t * CK + lane];
        if (tid < CK) dsts[tid] = dv;
    }
#pragma unroll
    for (int hh = 0; hh < 4; ++hh) {
        const int head = wv * 4 + hh;
        float e = -3.0e38f;
        if (lane < CK) {
            const float ee = s1[head * CN2 + sv] + s2[head * CN2 + dv];
            e = (ee > 0.f) ? ee : ALPHA * ee;
        }
        float m = e;
#pragma unroll
        for (int mm = 1; mm < 64; mm <<= 1) m = fmaxf(m, __shfl_xor(m, mm));
        const float p = (lane < CK) ? __expf(e - m) : 0.f;
        float s = p;
#pragma unroll
        for (int mm = 1; mm < 64; mm <<= 1) s += __shfl_xor(s, mm);
        if (lane < CK) wgt[head][lane] = p / s;
    }
    __syncthreads();

    const int c0   = tid * 8;
    const int head = tid >> 4;
    float acc[8] = {0.f, 0.f, 0.f, 0.f, 0.f, 0.f, 0.f, 0.f};
#pragma unroll
    for (int k = 0; k < CK; ++k) {
        const short8 hv = *reinterpret_cast<const short8*>(
            hm + (size_t)dsts[k] * (CNH * CHID) + c0);
        const float w = wgt[head][k];
#pragma unroll
        for (int j = 0; j < 8; ++j) acc[j] = fmaf(w, bf2f((u16)hv[j]), acc[j]);
    }
    short8 o;
#pragma unroll
    for (int j = 0; j < 8; ++j) {
        const float v = (acc[j] > 0.f) ? acc[j] : __expf(acc[j]) - 1.f;  // ELU
        o[j] = (short)f2bf(v);
    }
    *reinterpret_cast<short8*>(xout + (size_t)t * (CNH * CHID) + c0) = o;
}

// ---------------------------------------------------------------------------
// layer-2 fused scores + softmax + aggregate + ELU.  One 128-thread block
// per target; per-edge scores computed on the fly from h2 (L2-resident).
// ---------------------------------------------------------------------------
__global__ __launch_bounds__(128) void final_k(const float* __restrict__ h2,
                                               const float* __restrict__ a2,
                                               const int* __restrict__ src,
                                               const int* __restrict__ dst,
                                               float* __restrict__ out) {
    __shared__ float e1[CK], e2[CK], wgt[CK];
    __shared__ int dsts[CK];

    const int t    = blockIdx.x;
    const int tid  = threadIdx.x;
    const int wv   = tid >> 6;      // 0: src scores, 1: dst scores
    const int lane = tid & 63;

    // phase 1: 33 row-dots per wave (wave0: h2[src].a2[:128], wave1: h2[dst].a2[128:])
    const float* ap = a2 + wv * CHID + lane * 2;
    const float a0 = ap[0], a1v = ap[1];
    for (int k = 0; k < CK; ++k) {
        const int node = (wv == 0) ? src[t * CK + k] : dst[t * CK + k];
        const float2 hv = *reinterpret_cast<const float2*>(
            h2 + (size_t)node * CHID + lane * 2);
        float d = hv.x * a0 + hv.y * a1v;
#pragma unroll
        for (int m = 1; m < 64; m <<= 1) d += __shfl_xor(d, m);
        if (lane == 0) {
            if (wv == 0) e1[k] = d;
            else { e2[k] = d; dsts[k] = node; }
        }
    }
    __syncthreads();

    // phase 2: softmax over the 33 edges (one wave)
    if (tid < 64) {
        float e = -3.0e38f;
        if (tid < CK) {
            const float ee = e1[tid] + e2[tid];
            e = (ee > 0.f) ? ee : ALPHA * ee;
        }
        float m = e;
#pragma unroll
        for (int mm = 1; mm < 64; mm <<= 1) m = fmaxf(m, __shfl_xor(m, mm));
        const float p = (tid < CK) ? __expf(e - m) : 0.f;
        float s = p;
#pragma unroll
        for (int mm = 1; mm < 64; mm <<= 1) s += __shfl_xor(s, mm);
        if (tid < CK) wgt[tid] = p / s;
    }
    __syncthreads();

    // phase 3: aggregate (thread = one col) + ELU
    float acc = 0.f;
#pragma unroll
    for (int k = 0; k < CK; ++k)
        acc = fmaf(wgt[k], h2[(size_t)dsts[k] * CHID + tid], acc);
    out[(size_t)t * CHID + tid] = (acc > 0.f) ? acc : __expf(acc) - 1.f;
}

// ---------------------------------------------------------------------------
extern "C" void kernel_launch(void* const* d_in, const int* in_sizes, int n_in,
                              void* d_out, int out_size, void* d_ws, size_t ws_size,
                              hipStream_t stream) {
    const float* feats = (const float*)d_in[0];
    const float* W1    = (const float*)d_in[1];
    const float* a1    = (const float*)d_in[2];
    const float* W2    = (const float*)d_in[3];
    const float* a2    = (const float*)d_in[4];
    const int*   src1  = (const int*)d_in[5];
    const int*   dst1  = (const int*)d_in[6];
    const int*   src2  = (const int*)d_in[8];
    const int*   dst2  = (const int*)d_in[9];
    float* out = (float*)d_out;

    char* w = (char*)d_ws;
    u16*   fb   = (u16*)w;                 w += (size_t)CN2 * CIN * 2;
    u16*   w1t  = (u16*)w;                 w += (size_t)CNH * CIN * CHID * 2;
    u16*   w2t  = (u16*)w;                 w += (size_t)CNH * CHID * CHID * 2;
    u16*   h1b  = (u16*)w;                 w += (size_t)CN2 * CNH * CHID * 2;
    float* s1   = (float*)w;               w += (size_t)CNH * CN2 * 4;
    float* s2   = (float*)w;               w += (size_t)CNH * CN2 * 4;
    u16*   xb   = (u16*)w;                 w += (size_t)CN1 * CNH * CHID * 2;
    float* h2   = (float*)w;               w += (size_t)CN1 * CHID * 4;

    // ---- prep: convert inputs, zero h2 ----
    prep_k<<<dim3(2048 + 256 + 128 + 128), 256, 0, stream>>>(
        feats, fb, W1, w1t, W2, w2t, h2);

    // ---- layer 1: h1 = feats @ W1 (bf16 out) + fused s1/s2 scores ----
    // col-tile fastest: 8 consecutive blocks share one A-tile (L3 reuse)
    gemm_mfma<8, true, true><<<dim3((CNH * CHID) / 128, CN2 / 64), 256, 0, stream>>>(
        fb, CIN, w1t, CIN, h1b, nullptr, CNH * CHID, a1, s1, s2, CN2);

    // ---- layer-1 softmax + aggregate + ELU (block per target) ----
    agg1_k<<<dim3(CN1), 128, 0, stream>>>(s1, s2, src1, dst1, h1b, xb);

    // ---- layer 2: h2 += x @ W2 (split-K=8, atomic f32 accumulate) ----
    gemm_mfma<4, false, false><<<dim3(1, CN1 / 64, 8), 256, 0, stream>>>(
        xb, CNH * CHID, w2t, CNH * CHID, nullptr, h2, CHID,
        nullptr, nullptr, nullptr, 0);

    // ---- layer-2 fused scores + softmax + aggregate + ELU ----
    final_k<<<dim3(CN0), 128, 0, stream>>>(h2, a2, src2, dst2, out);
}

// Round 9
// 61.225 us; speedup vs baseline: 1.3221x; 1.3221x over previous
//
#include <hip/hip_runtime.h>
#include <math.h>

#define ALPHA 0.2f

constexpr int CN0 = 512, CN1 = 2048, CN2 = 8192, CK = 33;
constexpr int CIN = 256, CHID = 128, CNH = 8;

using u16    = unsigned short;
using f32x4  = __attribute__((ext_vector_type(4))) float;
using bf16x8 = __attribute__((ext_vector_type(8))) short;
using short8 = __attribute__((ext_vector_type(8))) short;

__device__ __forceinline__ u16 f2bf(float f) {
    unsigned u = __float_as_uint(f);
    u += 0x7fff + ((u >> 16) & 1);   // RNE
    return (u16)(u >> 16);
}
__device__ __forceinline__ float bf2f(u16 h) {
    return __uint_as_float(((unsigned)h) << 16);
}

#define GLD16(g, l)                                                        \
    __builtin_amdgcn_global_load_lds(                                      \
        (const __attribute__((address_space(1))) void*)(g),                \
        (__attribute__((address_space(3))) void*)(l), 16, 0, 0)

// ---------------------------------------------------------------------------
// prep: fused feats-convert + W1/W2 transpose-convert.
// ---------------------------------------------------------------------------
__global__ __launch_bounds__(256) void prep_k(const float* __restrict__ feats,
                                              u16* __restrict__ fb,
                                              const float* __restrict__ W1,
                                              u16* __restrict__ w1t,
                                              const float* __restrict__ W2,
                                              u16* __restrict__ w2t) {
    __shared__ float t[32][33];
    int b = blockIdx.x;
    if (b < 2048) {
        const int i = (b * 256 + threadIdx.x) * 4;
        const float4 v = *reinterpret_cast<const float4*>(feats + i);
        *reinterpret_cast<ushort4*>(fb + i) =
            make_ushort4(f2bf(v.x), f2bf(v.y), f2bf(v.z), f2bf(v.w));
        return;
    }
    b -= 2048;
    const float* ip;
    u16* op;
    int R, C, r0, c0;
    if (b < 256) {  // W1 head h
        const int h = b >> 5, w = b & 31;
        ip = W1 + (size_t)h * CIN * CHID;
        op = w1t + (size_t)h * CIN * CHID;
        R = CIN; C = CHID; r0 = (w >> 2) * 32; c0 = (w & 3) * 32;
    } else {        // W2
        b -= 256;
        ip = W2; op = w2t;
        R = CNH * CHID; C = CHID; r0 = (b >> 2) * 32; c0 = (b & 3) * 32;
    }
    const int tx = threadIdx.x & 31, ty = threadIdx.x >> 5;
#pragma unroll
    for (int i = 0; i < 4; ++i)
        t[ty + 8 * i][tx] = ip[(size_t)(r0 + ty + 8 * i) * C + c0 + tx];
    __syncthreads();
#pragma unroll
    for (int i = 0; i < 4; ++i)
        op[(size_t)(c0 + ty + 8 * i) * R + r0 + tx] = f2bf(t[tx][ty + 8 * i]);
}

// ---------------------------------------------------------------------------
// bf16 MFMA GEMM, 128x128 tile, BK=32, 4 waves, 2-phase double-buffered LDS.
// Grid: blockIdx.x = COL tile (FASTEST -> 8 consecutive blocks land on the 8
// XCDs sharing one A row-panel through L3; A fetched from HBM ~once),
// blockIdx.y = ROW tile, blockIdx.z = K-split (KSTEPS*32 each, Cf +z*csplit).
// BF16OUT: C staged through LDS (aliased over A/B buffers) -> dwordx4.
// SCORES: fused per-row dual dot with av (col tile == one head).
// ---------------------------------------------------------------------------
template <int KSTEPS, bool BF16OUT, bool SCORES>
__global__ __launch_bounds__(256) void gemm_mfma(const u16* __restrict__ A, int lda,
                                                 const u16* __restrict__ Bt, int ldb,
                                                 u16* __restrict__ Cb,
                                                 float* __restrict__ Cf, int ldc,
                                                 long csplit,
                                                 const float* __restrict__ av,
                                                 float* __restrict__ s1o,
                                                 float* __restrict__ s2o,
                                                 int snodes) {
    // smem: 2 x (8KB A-buf + 8KB B-buf) = 32KB; bf16 C-stage tile (34816B)
    // aliases the whole thing after the K-loop's final barrier.
    constexpr int SMEMSZ = BF16OUT ? (128 * 136 * 2) : 32768;
    __shared__ __attribute__((aligned(16))) char smem[SMEMSZ];

    const int tid  = threadIdx.x;
    const int lane = tid & 63;
    const int wave = tid >> 6;
    const int row0 = blockIdx.y * 128;
    const int col0 = blockIdx.x * 128;
    const int kbase = blockIdx.z * (KSTEPS * 32);
    const int wr = (wave >> 1) * 64;
    const int wc = (wave & 1) * 64;

    f32x4 acc[4][4];
#pragma unroll
    for (int m = 0; m < 4; ++m)
#pragma unroll
        for (int n = 0; n < 4; ++n) acc[m][n] = (f32x4){0.f, 0.f, 0.f, 0.f};

    // staging: swizzled global source chunk so fragment ds_read_b128 is ~free
    const int r0c = tid >> 2;
    const int cs0 = tid & 3;
    const int c0  = (cs0 - (r0c >> 1)) & 3;
    const int r1c = r0c + 64;

    const u16* ga0 = A + (size_t)(row0 + r0c) * lda + kbase + c0 * 8;
    const u16* ga1 = A + (size_t)(row0 + r1c) * lda + kbase + c0 * 8;
    const u16* gb0 = Bt + (size_t)(col0 + r0c) * ldb + kbase + c0 * 8;
    const u16* gb1 = Bt + (size_t)(col0 + r1c) * ldb + kbase + c0 * 8;

    auto STAGE = [&](int s) {
        const int k0 = s * 32;
        char* base = smem + (s & 1) * 16384;
        u16* as = (u16*)base + wave * 512;
        u16* bs = (u16*)(base + 8192) + wave * 512;
        GLD16(ga0 + k0, as);
        GLD16(ga1 + k0, as + 2048);
        GLD16(gb0 + k0, bs);
        GLD16(gb1 + k0, bs + 2048);
    };

    STAGE(0);
    __syncthreads();   // vmcnt(0) drain: buf0 resident

    for (int s = 0; s < KSTEPS; ++s) {
        if (s + 1 < KSTEPS) STAGE(s + 1);   // prefetch into other buffer

        const u16* Acur = (const u16*)(smem + (s & 1) * 16384);
        const u16* Bcur = Acur + 4096;

        bf16x8 af[4], bfr[4];
#pragma unroll
        for (int m = 0; m < 4; ++m) {
            const int rt = wr + m * 16 + (lane & 15);
            const int cs = ((lane >> 4) + (rt >> 1)) & 3;
            af[m] = *reinterpret_cast<const bf16x8*>(Acur + rt * 32 + cs * 8);
            const int rt2 = wc + m * 16 + (lane & 15);
            const int cs2 = ((lane >> 4) + (rt2 >> 1)) & 3;
            bfr[m] = *reinterpret_cast<const bf16x8*>(Bcur + rt2 * 32 + cs2 * 8);
        }
#pragma unroll
        for (int m = 0; m < 4; ++m)
#pragma unroll
            for (int n = 0; n < 4; ++n)
                acc[m][n] = __builtin_amdgcn_mfma_f32_16x16x32_bf16(
                    af[m], bfr[n], acc[m][n], 0, 0, 0);

        __syncthreads();   // drains prefetch (vmcnt0) + guards buffer reuse
    }

    // C/D layout: col = lane&15, row = (lane>>4)*4 + q   [m89-verified]
    if constexpr (BF16OUT) {
        u16* Cs = (u16*)smem;   // aliases A/B buffers (dead after last barrier)
#pragma unroll
        for (int m = 0; m < 4; ++m) {
            const int rr = wr + m * 16 + (lane >> 4) * 4;
#pragma unroll
            for (int n = 0; n < 4; ++n) {
                const int cc = wc + n * 16 + (lane & 15);
#pragma unroll
                for (int q = 0; q < 4; ++q)
                    Cs[(rr + q) * 136 + cc] = f2bf(acc[m][n][q]);
            }
        }
        __syncthreads();
#pragma unroll
        for (int i = 0; i < 8; ++i) {
            const int cid = i * 256 + tid;       // 0..2047
            const int r  = cid >> 4;
            const int kc = cid & 15;
            const int4 v = *reinterpret_cast<const int4*>(&Cs[r * 136 + kc * 8]);
            *reinterpret_cast<int4*>(&Cb[(long)(row0 + r) * ldc + col0 + kc * 8]) = v;
        }
    } else {
        const long cbase = (long)blockIdx.z * csplit;
#pragma unroll
        for (int m = 0; m < 4; ++m) {
            const int rr = row0 + wr + m * 16 + (lane >> 4) * 4;
#pragma unroll
            for (int n = 0; n < 4; ++n) {
                const int cc = col0 + wc + n * 16 + (lane & 15);
#pragma unroll
                for (int q = 0; q < 4; ++q)
                    Cf[cbase + (long)(rr + q) * ldc + cc] = acc[m][n][q];
            }
        }
    }

    if constexpr (SCORES) {
        __shared__ float sred1[2][128];
        __shared__ float sred2[2][128];
        const int head = blockIdx.x;
        float av1[4], av2[4];
#pragma unroll
        for (int n = 0; n < 4; ++n) {
            const int c = wc + n * 16 + (lane & 15);
            av1[n] = av[head * 2 * CHID + c];
            av2[n] = av[head * 2 * CHID + CHID + c];
        }
        float p1[4][4], p2[4][4];
#pragma unroll
        for (int m = 0; m < 4; ++m)
#pragma unroll
            for (int q = 0; q < 4; ++q) {
                float t1 = 0.f, t2 = 0.f;
#pragma unroll
                for (int n = 0; n < 4; ++n) {
                    t1 = fmaf(acc[m][n][q], av1[n], t1);
                    t2 = fmaf(acc[m][n][q], av2[n], t2);
                }
#pragma unroll
                for (int mk = 1; mk < 16; mk <<= 1) {
                    t1 += __shfl_xor(t1, mk);
                    t2 += __shfl_xor(t2, mk);
                }
                p1[m][q] = t1;
                p2[m][q] = t2;
            }
        if ((lane & 15) == 0) {
            const int g = lane >> 4;
#pragma unroll
            for (int m = 0; m < 4; ++m)
#pragma unroll
                for (int q = 0; q < 4; ++q) {
                    sred1[wave & 1][wr + m * 16 + g * 4 + q] = p1[m][q];
                    sred2[wave & 1][wr + m * 16 + g * 4 + q] = p2[m][q];
                }
        }
        __syncthreads();
        if (tid < 128) {
            s1o[head * snodes + row0 + tid] = sred1[0][tid] + sred1[1][tid];
            s2o[head * snodes + row0 + tid] = sred2[0][tid] + sred2[1][tid];
        }
    }
}

// ---------------------------------------------------------------------------
// layer-1 softmax + aggregate + ELU.  One 128-thread block per target.
// ---------------------------------------------------------------------------
__global__ __launch_bounds__(128) void agg1_k(const float* __restrict__ s1,
                                              const float* __restrict__ s2,
                                              const int* __restrict__ src,
                                              const int* __restrict__ dst,
                                              const u16* __restrict__ hm,
                                              u16* __restrict__ xout) {
    __shared__ float wgt[CNH][CK];
    __shared__ int dsts[CK];

    const int t    = blockIdx.x;
    const int tid  = threadIdx.x;
    const int wv   = tid >> 6;
    const int lane = tid & 63;

    int sv = 0, dv = 0;
    if (lane < CK) {
        sv = src[t * CK + lane];
        dv = dst[t * CK + lane];
        if (tid < CK) dsts[tid] = dv;
    }
#pragma unroll
    for (int hh = 0; hh < 4; ++hh) {
        const int head = wv * 4 + hh;
        float e = -3.0e38f;
        if (lane < CK) {
            const float ee = s1[head * CN2 + sv] + s2[head * CN2 + dv];
            e = (ee > 0.f) ? ee : ALPHA * ee;
        }
        float m = e;
#pragma unroll
        for (int mm = 1; mm < 64; mm <<= 1) m = fmaxf(m, __shfl_xor(m, mm));
        const float p = (lane < CK) ? __expf(e - m) : 0.f;
        float s = p;
#pragma unroll
        for (int mm = 1; mm < 64; mm <<= 1) s += __shfl_xor(s, mm);
        if (lane < CK) wgt[head][lane] = p / s;
    }
    __syncthreads();

    const int c0   = tid * 8;
    const int head = tid >> 4;
    float acc[8] = {0.f, 0.f, 0.f, 0.f, 0.f, 0.f, 0.f, 0.f};
#pragma unroll
    for (int k = 0; k < CK; ++k) {
        const short8 hv = *reinterpret_cast<const short8*>(
            hm + (size_t)dsts[k] * (CNH * CHID) + c0);
        const float w = wgt[head][k];
#pragma unroll
        for (int j = 0; j < 8; ++j) acc[j] = fmaf(w, bf2f((u16)hv[j]), acc[j]);
    }
    short8 o;
#pragma unroll
    for (int j = 0; j < 8; ++j) {
        const float v = (acc[j] > 0.f) ? acc[j] : __expf(acc[j]) - 1.f;  // ELU
        o[j] = (short)f2bf(v);
    }
    *reinterpret_cast<short8*>(xout + (size_t)t * (CNH * CHID) + c0) = o;
}

// ---------------------------------------------------------------------------
// layer-2: reduce split-K partials -> h2 f32, + scores. one wave per node
// ---------------------------------------------------------------------------
__global__ __launch_bounds__(256) void scores2_k(const float* __restrict__ part,
                                                 const float* __restrict__ a,
                                                 float* __restrict__ h2,
                                                 float* __restrict__ s1,
                                                 float* __restrict__ s2) {
    const int wid  = (blockIdx.x * 256 + threadIdx.x) >> 6;   // node
    const int lane = threadIdx.x & 63;
    const int j = lane * 2;
    float x0 = 0.f, x1 = 0.f;
#pragma unroll
    for (int sp = 0; sp < 8; ++sp) {
        const float2 v = *reinterpret_cast<const float2*>(
            part + (size_t)sp * CN1 * CHID + (size_t)wid * CHID + j);
        x0 += v.x; x1 += v.y;
    }
    *reinterpret_cast<float2*>(h2 + (size_t)wid * CHID + j) = make_float2(x0, x1);
    float d1 = x0 * a[j] + x1 * a[j + 1];
    float d2 = x0 * a[CHID + j] + x1 * a[CHID + j + 1];
#pragma unroll
    for (int m = 1; m < 64; m <<= 1) {
        d1 += __shfl_xor(d1, m);
        d2 += __shfl_xor(d2, m);
    }
    if (lane == 0) { s1[wid] = d1; s2[wid] = d2; }
}

// ---------------------------------------------------------------------------
// layer-2 softmax+aggregate+ELU: one wave per target; f32 in/out
// ---------------------------------------------------------------------------
__global__ __launch_bounds__(256) void agg2_k(const float* __restrict__ s1,
                                              const float* __restrict__ s2,
                                              const int* __restrict__ src,
                                              const int* __restrict__ dst,
                                              const float* __restrict__ h2,
                                              float* __restrict__ out) {
    const int t    = (blockIdx.x * 256 + threadIdx.x) >> 6;
    const int lane = threadIdx.x & 63;

    float e = -3.0e38f;
    int dv = 0;
    if (lane < CK) {
        const int sv = src[t * CK + lane];
        dv = dst[t * CK + lane];
        const float ee = s1[sv] + s2[dv];
        e = (ee > 0.f) ? ee : ALPHA * ee;
    }
    float m = e;
#pragma unroll
    for (int mm = 1; mm < 64; mm <<= 1) m = fmaxf(m, __shfl_xor(m, mm));
    float p = (lane < CK) ? __expf(e - m) : 0.f;
    float ssum = p;
#pragma unroll
    for (int mm = 1; mm < 64; mm <<= 1) ssum += __shfl_xor(ssum, mm);
    const float invs = 1.f / ssum;

    float a0 = 0.f, a1 = 0.f;
#pragma unroll
    for (int k = 0; k < CK; ++k) {
        const float w = __shfl(p, k) * invs;
        const int d = __shfl(dv, k);
        const float2 hv = *reinterpret_cast<const float2*>(h2 + (size_t)d * CHID + lane * 2);
        a0 = fmaf(w, hv.x, a0);
        a1 = fmaf(w, hv.y, a1);
    }
    a0 = (a0 > 0.f) ? a0 : __expf(a0) - 1.f;
    a1 = (a1 > 0.f) ? a1 : __expf(a1) - 1.f;
    *reinterpret_cast<float2*>(out + (size_t)t * CHID + lane * 2) = make_float2(a0, a1);
}

// ---------------------------------------------------------------------------
extern "C" void kernel_launch(void* const* d_in, const int* in_sizes, int n_in,
                              void* d_out, int out_size, void* d_ws, size_t ws_size,
                              hipStream_t stream) {
    const float* feats = (const float*)d_in[0];
    const float* W1    = (const float*)d_in[1];
    const float* a1    = (const float*)d_in[2];
    const float* W2    = (const float*)d_in[3];
    const float* a2    = (const float*)d_in[4];
    const int*   src1  = (const int*)d_in[5];
    const int*   dst1  = (const int*)d_in[6];
    const int*   src2  = (const int*)d_in[8];
    const int*   dst2  = (const int*)d_in[9];
    float* out = (float*)d_out;

    char* w = (char*)d_ws;
    u16*   fb   = (u16*)w;                 w += (size_t)CN2 * CIN * 2;
    u16*   w1t  = (u16*)w;                 w += (size_t)CNH * CIN * CHID * 2;
    u16*   w2t  = (u16*)w;                 w += (size_t)CNH * CHID * CHID * 2;
    u16*   h1b  = (u16*)w;                 w += (size_t)CN2 * CNH * CHID * 2;
    float* s1   = (float*)w;               w += (size_t)CNH * CN2 * 4;
    float* s2   = (float*)w;               w += (size_t)CNH * CN2 * 4;
    u16*   xb   = (u16*)w;                 w += (size_t)CN1 * CNH * CHID * 2;
    float* part = (float*)w;               w += (size_t)8 * CN1 * CHID * 4;
    float* h2   = (float*)w;               w += (size_t)CN1 * CHID * 4;
    float* s21  = (float*)w;               w += (size_t)CN1 * 4;
    float* s22  = (float*)w;               w += (size_t)CN1 * 4;

    // ---- fused input conversion ----
    prep_k<<<dim3(2048 + 256 + 128), 256, 0, stream>>>(feats, fb, W1, w1t, W2, w2t);

    // ---- layer 1: h1 = feats @ W1 (bf16 out) + fused s1/s2 scores ----
    // col-tile FASTEST: 8 consecutive blocks share one A row-panel via L3
    gemm_mfma<8, true, true><<<dim3((CNH * CHID) / 128, CN2 / 128), 256, 0, stream>>>(
        fb, CIN, w1t, CIN, h1b, nullptr, CNH * CHID, 0, a1, s1, s2, CN2);

    // ---- layer-1 softmax + aggregate + ELU (block per target) ----
    agg1_k<<<dim3(CN1), 128, 0, stream>>>(s1, s2, src1, dst1, h1b, xb);

    // ---- layer 2: h2 = x @ W2 (split-K=8 partials, f32) ----
    gemm_mfma<4, false, false><<<dim3(1, CN1 / 128, 8), 256, 0, stream>>>(
        xb, CNH * CHID, w2t, CNH * CHID, nullptr, part, CHID, (long)CN1 * CHID,
        nullptr, nullptr, nullptr, 0);

    scores2_k<<<dim3(CN1 / 4), 256, 0, stream>>>(part, a2, h2, s21, s22);

    agg2_k<<<dim3(CN0 / 4), 256, 0, stream>>>(s21, s22, src2, dst2, h2, out);
}

// Round 10
// 57.743 us; speedup vs baseline: 1.4018x; 1.0603x over previous
//
#include <hip/hip_runtime.h>
#include <math.h>

#define ALPHA 0.2f

constexpr int CN0 = 512, CN1 = 2048, CN2 = 8192, CK = 33;
constexpr int CIN = 256, CHID = 128, CNH = 8;

using u16    = unsigned short;
using f32x4  = __attribute__((ext_vector_type(4))) float;
using bf16x8 = __attribute__((ext_vector_type(8))) short;
using short8 = __attribute__((ext_vector_type(8))) short;

__device__ __forceinline__ u16 f2bf(float f) {
    unsigned u = __float_as_uint(f);
    u += 0x7fff + ((u >> 16) & 1);   // RNE
    return (u16)(u >> 16);
}
__device__ __forceinline__ float bf2f(u16 h) {
    return __uint_as_float(((unsigned)h) << 16);
}

#define GLD16(g, l)                                                        \
    __builtin_amdgcn_global_load_lds(                                      \
        (const __attribute__((address_space(1))) void*)(g),                \
        (__attribute__((address_space(3))) void*)(l), 16, 0, 0)

// ---------------------------------------------------------------------------
// prep: feats->bf16, W1/W2 transpose->bf16, pvec = W1_h @ a1 halves (f32).
// blocks [0,2048): feats; [2048,2304): W1 T; [2304,2432): W2 T;
// [2432,2448): pvec[h][half][j] = sum_c W1[h][j][c] * a1[h][half*128+c]
// ---------------------------------------------------------------------------
__global__ __launch_bounds__(256) void prep_k(const float* __restrict__ feats,
                                              u16* __restrict__ fb,
                                              const float* __restrict__ W1,
                                              u16* __restrict__ w1t,
                                              const float* __restrict__ W2,
                                              u16* __restrict__ w2t,
                                              const float* __restrict__ a1,
                                              float* __restrict__ pvec) {
    __shared__ float t[32][33];
    int b = blockIdx.x;
    if (b < 2048) {
        const int i = (b * 256 + threadIdx.x) * 4;
        const float4 v = *reinterpret_cast<const float4*>(feats + i);
        *reinterpret_cast<ushort4*>(fb + i) =
            make_ushort4(f2bf(v.x), f2bf(v.y), f2bf(v.z), f2bf(v.w));
        return;
    }
    if (b >= 2432) {   // pvec: 16 blocks, one per (head, half)
        const int i = b - 2432;
        const int h = i >> 1, half = i & 1;
        const int j = threadIdx.x;   // 0..255
        const float* wrow = W1 + (size_t)h * CIN * CHID + (size_t)j * CHID;
        const float* ah   = a1 + h * 2 * CHID + half * CHID;
        float d = 0.f;
#pragma unroll 8
        for (int c = 0; c < CHID; ++c) d = fmaf(wrow[c], ah[c], d);
        pvec[(h * 2 + half) * CIN + j] = d;
        return;
    }
    b -= 2048;
    const float* ip;
    u16* op;
    int R, C, r0, c0;
    if (b < 256) {  // W1 head h
        const int h = b >> 5, w = b & 31;
        ip = W1 + (size_t)h * CIN * CHID;
        op = w1t + (size_t)h * CIN * CHID;
        R = CIN; C = CHID; r0 = (w >> 2) * 32; c0 = (w & 3) * 32;
    } else {        // W2
        b -= 256;
        ip = W2; op = w2t;
        R = CNH * CHID; C = CHID; r0 = (b >> 2) * 32; c0 = (b & 3) * 32;
    }
    const int tx = threadIdx.x & 31, ty = threadIdx.x >> 5;
#pragma unroll
    for (int i = 0; i < 4; ++i)
        t[ty + 8 * i][tx] = ip[(size_t)(r0 + ty + 8 * i) * C + c0 + tx];
    __syncthreads();
#pragma unroll
    for (int i = 0; i < 4; ++i)
        op[(size_t)(c0 + ty + 8 * i) * R + r0 + tx] = f2bf(t[tx][ty + 8 * i]);
}

// ---------------------------------------------------------------------------
// layer-1 scores: s1[h][n] = fb[n] . pvec[h][0], s2[h][n] = fb[n] . pvec[h][1]
// one wave per node.
// ---------------------------------------------------------------------------
__global__ __launch_bounds__(256) void sgemm1_k(const u16* __restrict__ fb,
                                                const float* __restrict__ pvec,
                                                float* __restrict__ s1,
                                                float* __restrict__ s2) {
    const int node = (blockIdx.x * 256 + threadIdx.x) >> 6;
    const int lane = threadIdx.x & 63;
    const ushort4 hv = *reinterpret_cast<const ushort4*>(fb + (size_t)node * CIN + lane * 4);
    const float v0 = bf2f(hv.x), v1 = bf2f(hv.y), v2 = bf2f(hv.z), v3 = bf2f(hv.w);
#pragma unroll
    for (int h = 0; h < CNH; ++h) {
        const float4 p1 = *reinterpret_cast<const float4*>(pvec + (h * 2 + 0) * CIN + lane * 4);
        const float4 p2 = *reinterpret_cast<const float4*>(pvec + (h * 2 + 1) * CIN + lane * 4);
        float d1 = v0 * p1.x + v1 * p1.y + v2 * p1.z + v3 * p1.w;
        float d2 = v0 * p2.x + v1 * p2.y + v2 * p2.z + v3 * p2.w;
#pragma unroll
        for (int m = 1; m < 64; m <<= 1) {
            d1 += __shfl_xor(d1, m);
            d2 += __shfl_xor(d2, m);
        }
        if (lane == 0) {
            s1[h * CN2 + node] = d1;
            s2[h * CN2 + node] = d2;
        }
    }
}

// ---------------------------------------------------------------------------
// layer-1 softmax + feats-gather-aggregate (NO projection, NO ELU here).
// One 128-thread block per target:
//   phase 1: 8 head-softmaxes into LDS wgt[8][33]
//   phase 2: g[h][t][c] = sum_k wgt[h][k] * fb[dst[k]][c]  (bf16 out)
// ---------------------------------------------------------------------------
__global__ __launch_bounds__(128) void agg1g_k(const float* __restrict__ s1,
                                               const float* __restrict__ s2,
                                               const int* __restrict__ src,
                                               const int* __restrict__ dst,
                                               const u16* __restrict__ fb,
                                               u16* __restrict__ gb) {
    __shared__ float wgt[CNH][CK];
    __shared__ int dsts[CK];

    const int t    = blockIdx.x;
    const int tid  = threadIdx.x;
    const int wv   = tid >> 6;
    const int lane = tid & 63;

    int sv = 0, dv = 0;
    if (lane < CK) {
        sv = src[t * CK + lane];
        dv = dst[t * CK + lane];
        if (tid < CK) dsts[tid] = dv;
    }
#pragma unroll
    for (int hh = 0; hh < 4; ++hh) {
        const int head = wv * 4 + hh;
        float e = -3.0e38f;
        if (lane < CK) {
            const float ee = s1[head * CN2 + sv] + s2[head * CN2 + dv];
            e = (ee > 0.f) ? ee : ALPHA * ee;
        }
        float m = e;
#pragma unroll
        for (int mm = 1; mm < 64; mm <<= 1) m = fmaxf(m, __shfl_xor(m, mm));
        const float p = (lane < CK) ? __expf(e - m) : 0.f;
        float s = p;
#pragma unroll
        for (int mm = 1; mm < 64; mm <<= 1) s += __shfl_xor(s, mm);
        if (lane < CK) wgt[head][lane] = p / s;
    }
    __syncthreads();

    // phase 2: thread owns feats col pair c2 = 2*tid
    const int c2 = tid * 2;
    float acc[CNH][2];
#pragma unroll
    for (int h = 0; h < CNH; ++h) { acc[h][0] = 0.f; acc[h][1] = 0.f; }
#pragma unroll 4
    for (int k = 0; k < CK; ++k) {
        const unsigned w2 = *reinterpret_cast<const unsigned*>(
            fb + (size_t)dsts[k] * CIN + c2);
        const float f0 = bf2f((u16)(w2 & 0xffff));
        const float f1 = bf2f((u16)(w2 >> 16));
#pragma unroll
        for (int h = 0; h < CNH; ++h) {
            const float wk = wgt[h][k];
            acc[h][0] = fmaf(wk, f0, acc[h][0]);
            acc[h][1] = fmaf(wk, f1, acc[h][1]);
        }
    }
#pragma unroll
    for (int h = 0; h < CNH; ++h) {
        const unsigned o = ((unsigned)f2bf(acc[h][1]) << 16) | f2bf(acc[h][0]);
        *reinterpret_cast<unsigned*>(gb + ((size_t)h * CN1 + t) * CIN + c2) = o;
    }
}

// ---------------------------------------------------------------------------
// bf16 MFMA GEMM, 128x128 tile, BK=32, 4 waves, 2-phase double-buffered LDS.
// HEADSPLIT: blockIdx.z = head; A/Bt get per-head base, C col offset = h*128.
// else:      blockIdx.z = K-split (KSTEPS*32 each, Cf += z*csplit).
// BF16OUT: C staged through LDS (aliased over A/B bufs) -> dwordx4; optional ELU.
// ---------------------------------------------------------------------------
template <int KSTEPS, bool BF16OUT, bool ELUOUT, bool HEADSPLIT>
__global__ __launch_bounds__(256) void gemm_mfma(const u16* __restrict__ A, int lda,
                                                 const u16* __restrict__ Bt, int ldb,
                                                 u16* __restrict__ Cb,
                                                 float* __restrict__ Cf, int ldc,
                                                 long csplit) {
    constexpr int SMEMSZ = BF16OUT ? (128 * 136 * 2) : 32768;
    __shared__ __attribute__((aligned(16))) char smem[SMEMSZ];

    const int tid  = threadIdx.x;
    const int lane = tid & 63;
    const int wave = tid >> 6;
    const int row0 = blockIdx.y * 128;

    int kbase, bcol0, ccol0;
    if constexpr (HEADSPLIT) {
        A  += (size_t)blockIdx.z * CN1 * CIN;
        Bt += (size_t)blockIdx.z * CHID * CIN;
        kbase = 0; bcol0 = 0; ccol0 = blockIdx.z * CHID;
    } else {
        kbase = blockIdx.z * (KSTEPS * 32);
        bcol0 = blockIdx.x * 128;
        ccol0 = bcol0;
    }
    const int wr = (wave >> 1) * 64;
    const int wc = (wave & 1) * 64;

    f32x4 acc[4][4];
#pragma unroll
    for (int m = 0; m < 4; ++m)
#pragma unroll
        for (int n = 0; n < 4; ++n) acc[m][n] = (f32x4){0.f, 0.f, 0.f, 0.f};

    const int r0c = tid >> 2;
    const int cs0 = tid & 3;
    const int c0  = (cs0 - (r0c >> 1)) & 3;
    const int r1c = r0c + 64;

    const u16* ga0 = A + (size_t)(row0 + r0c) * lda + kbase + c0 * 8;
    const u16* ga1 = A + (size_t)(row0 + r1c) * lda + kbase + c0 * 8;
    const u16* gb0 = Bt + (size_t)(bcol0 + r0c) * ldb + kbase + c0 * 8;
    const u16* gb1 = Bt + (size_t)(bcol0 + r1c) * ldb + kbase + c0 * 8;

    auto STAGE = [&](int s) {
        const int k0 = s * 32;
        char* base = smem + (s & 1) * 16384;
        u16* as = (u16*)base + wave * 512;
        u16* bs = (u16*)(base + 8192) + wave * 512;
        GLD16(ga0 + k0, as);
        GLD16(ga1 + k0, as + 2048);
        GLD16(gb0 + k0, bs);
        GLD16(gb1 + k0, bs + 2048);
    };

    STAGE(0);
    __syncthreads();

    for (int s = 0; s < KSTEPS; ++s) {
        if (s + 1 < KSTEPS) STAGE(s + 1);

        const u16* Acur = (const u16*)(smem + (s & 1) * 16384);
        const u16* Bcur = Acur + 4096;

        bf16x8 af[4], bfr[4];
#pragma unroll
        for (int m = 0; m < 4; ++m) {
            const int rt = wr + m * 16 + (lane & 15);
            const int cs = ((lane >> 4) + (rt >> 1)) & 3;
            af[m] = *reinterpret_cast<const bf16x8*>(Acur + rt * 32 + cs * 8);
            const int rt2 = wc + m * 16 + (lane & 15);
            const int cs2 = ((lane >> 4) + (rt2 >> 1)) & 3;
            bfr[m] = *reinterpret_cast<const bf16x8*>(Bcur + rt2 * 32 + cs2 * 8);
        }
#pragma unroll
        for (int m = 0; m < 4; ++m)
#pragma unroll
            for (int n = 0; n < 4; ++n)
                acc[m][n] = __builtin_amdgcn_mfma_f32_16x16x32_bf16(
                    af[m], bfr[n], acc[m][n], 0, 0, 0);

        __syncthreads();
    }

    // C/D layout: col = lane&15, row = (lane>>4)*4 + q   [m89-verified]
    if constexpr (BF16OUT) {
        u16* Cs = (u16*)smem;
#pragma unroll
        for (int m = 0; m < 4; ++m) {
            const int rr = wr + m * 16 + (lane >> 4) * 4;
#pragma unroll
            for (int n = 0; n < 4; ++n) {
                const int cc = wc + n * 16 + (lane & 15);
#pragma unroll
                for (int q = 0; q < 4; ++q) {
                    float v = acc[m][n][q];
                    if (ELUOUT) v = (v > 0.f) ? v : __expf(v) - 1.f;
                    Cs[(rr + q) * 136 + cc] = f2bf(v);
                }
            }
        }
        __syncthreads();
#pragma unroll
        for (int i = 0; i < 8; ++i) {
            const int cid = i * 256 + tid;
            const int r  = cid >> 4;
            const int kc = cid & 15;
            const int4 v = *reinterpret_cast<const int4*>(&Cs[r * 136 + kc * 8]);
            *reinterpret_cast<int4*>(&Cb[(long)(row0 + r) * ldc + ccol0 + kc * 8]) = v;
        }
    } else {
        const long cbase = HEADSPLIT ? 0 : (long)blockIdx.z * csplit;
#pragma unroll
        for (int m = 0; m < 4; ++m) {
            const int rr = row0 + wr + m * 16 + (lane >> 4) * 4;
#pragma unroll
            for (int n = 0; n < 4; ++n) {
                const int cc = ccol0 + wc + n * 16 + (lane & 15);
#pragma unroll
                for (int q = 0; q < 4; ++q)
                    Cf[cbase + (long)(rr + q) * ldc + cc] = acc[m][n][q];
            }
        }
    }
}

// ---------------------------------------------------------------------------
// layer-2: reduce split-K partials -> h2 f32, + scores. one wave per node
// ---------------------------------------------------------------------------
__global__ __launch_bounds__(256) void scores2_k(const float* __restrict__ part,
                                                 const float* __restrict__ a,
                                                 float* __restrict__ h2,
                                                 float* __restrict__ s1,
                                                 float* __restrict__ s2) {
    const int wid  = (blockIdx.x * 256 + threadIdx.x) >> 6;   // node
    const int lane = threadIdx.x & 63;
    const int j = lane * 2;
    float x0 = 0.f, x1 = 0.f;
#pragma unroll
    for (int sp = 0; sp < 8; ++sp) {
        const float2 v = *reinterpret_cast<const float2*>(
            part + (size_t)sp * CN1 * CHID + (size_t)wid * CHID + j);
        x0 += v.x; x1 += v.y;
    }
    *reinterpret_cast<float2*>(h2 + (size_t)wid * CHID + j) = make_float2(x0, x1);
    float d1 = x0 * a[j] + x1 * a[j + 1];
    float d2 = x0 * a[CHID + j] + x1 * a[CHID + j + 1];
#pragma unroll
    for (int m = 1; m < 64; m <<= 1) {
        d1 += __shfl_xor(d1, m);
        d2 += __shfl_xor(d2, m);
    }
    if (lane == 0) { s1[wid] = d1; s2[wid] = d2; }
}

// ---------------------------------------------------------------------------
// layer-2 softmax+aggregate+ELU: one wave per target; f32 in/out
// ---------------------------------------------------------------------------
__global__ __launch_bounds__(256) void agg2_k(const float* __restrict__ s1,
                                              const float* __restrict__ s2,
                                              const int* __restrict__ src,
                                              const int* __restrict__ dst,
                                              const float* __restrict__ h2,
                                              float* __restrict__ out) {
    const int t    = (blockIdx.x * 256 + threadIdx.x) >> 6;
    const int lane = threadIdx.x & 63;

    float e = -3.0e38f;
    int dv = 0;
    if (lane < CK) {
        const int sv = src[t * CK + lane];
        dv = dst[t * CK + lane];
        const float ee = s1[sv] + s2[dv];
        e = (ee > 0.f) ? ee : ALPHA * ee;
    }
    float m = e;
#pragma unroll
    for (int mm = 1; mm < 64; mm <<= 1) m = fmaxf(m, __shfl_xor(m, mm));
    float p = (lane < CK) ? __expf(e - m) : 0.f;
    float ssum = p;
#pragma unroll
    for (int mm = 1; mm < 64; mm <<= 1) ssum += __shfl_xor(ssum, mm);
    const float invs = 1.f / ssum;

    float a0 = 0.f, a1 = 0.f;
#pragma unroll
    for (int k = 0; k < CK; ++k) {
        const float w = __shfl(p, k) * invs;
        const int d = __shfl(dv, k);
        const float2 hv = *reinterpret_cast<const float2*>(h2 + (size_t)d * CHID + lane * 2);
        a0 = fmaf(w, hv.x, a0);
        a1 = fmaf(w, hv.y, a1);
    }
    a0 = (a0 > 0.f) ? a0 : __expf(a0) - 1.f;
    a1 = (a1 > 0.f) ? a1 : __expf(a1) - 1.f;
    *reinterpret_cast<float2*>(out + (size_t)t * CHID + lane * 2) = make_float2(a0, a1);
}

// ---------------------------------------------------------------------------
extern "C" void kernel_launch(void* const* d_in, const int* in_sizes, int n_in,
                              void* d_out, int out_size, void* d_ws, size_t ws_size,
                              hipStream_t stream) {
    const float* feats = (const float*)d_in[0];
    const float* W1    = (const float*)d_in[1];
    const float* a1    = (const float*)d_in[2];
    const float* W2    = (const float*)d_in[3];
    const float* a2    = (const float*)d_in[4];
    const int*   src1  = (const int*)d_in[5];
    const int*   dst1  = (const int*)d_in[6];
    const int*   src2  = (const int*)d_in[8];
    const int*   dst2  = (const int*)d_in[9];
    float* out = (float*)d_out;

    char* w = (char*)d_ws;
    u16*   fb   = (u16*)w;                 w += (size_t)CN2 * CIN * 2;          // 4 MB
    u16*   w1t  = (u16*)w;                 w += (size_t)CNH * CIN * CHID * 2;
    u16*   w2t  = (u16*)w;                 w += (size_t)CNH * CHID * CHID * 2;
    float* pvec = (float*)w;               w += (size_t)CNH * 2 * CIN * 4;      // 16 KB
    float* s1   = (float*)w;               w += (size_t)CNH * CN2 * 4;
    float* s2   = (float*)w;               w += (size_t)CNH * CN2 * 4;
    u16*   gb   = (u16*)w;                 w += (size_t)CNH * CN1 * CIN * 2;    // 8 MB
    u16*   xb   = (u16*)w;                 w += (size_t)CN1 * CNH * CHID * 2;   // 4 MB
    float* part = (float*)w;               w += (size_t)8 * CN1 * CHID * 4;     // 8 MB
    float* h2   = (float*)w;               w += (size_t)CN1 * CHID * 4;
    float* s21  = (float*)w;               w += (size_t)CN1 * 4;
    float* s22  = (float*)w;               w += (size_t)CN1 * 4;

    // ---- prep: convert feats/W1/W2, compute pvec = W1_h @ a1 halves ----
    prep_k<<<dim3(2048 + 256 + 128 + 16), 256, 0, stream>>>(
        feats, fb, W1, w1t, W2, w2t, a1, pvec);

    // ---- layer-1 scores for all 8192 nodes (tiny GEMV) ----
    sgemm1_k<<<dim3(CN2 / 4), 256, 0, stream>>>(fb, pvec, s1, s2);

    // ---- layer-1 softmax + feats-aggregate -> g [8][2048][256] bf16 ----
    agg1g_k<<<dim3(CN1), 128, 0, stream>>>(s1, s2, src1, dst1, fb, gb);

    // ---- project: x[t, h*128+c] = ELU(g[h][t] @ W1_h), bf16 out ----
    gemm_mfma<8, true, true, true><<<dim3(1, CN1 / 128, CNH), 256, 0, stream>>>(
        gb, CIN, w1t, CIN, xb, nullptr, CNH * CHID, 0);

    // ---- layer 2: h2 = x @ W2 (split-K=8 partials, f32) ----
    gemm_mfma<4, false, false, false><<<dim3(1, CN1 / 128, 8), 256, 0, stream>>>(
        xb, CNH * CHID, w2t, CNH * CHID, nullptr, part, CHID, (long)CN1 * CHID);

    scores2_k<<<dim3(CN1 / 4), 256, 0, stream>>>(part, a2, h2, s21, s22);

    agg2_k<<<dim3(CN0 / 4), 256, 0, stream>>>(s21, s22, src2, dst2, h2, out);
}

// Round 11
// 52.806 us; speedup vs baseline: 1.5329x; 1.0935x over previous
//
#include <hip/hip_runtime.h>
#include <math.h>

#define ALPHA 0.2f

constexpr int CN0 = 512, CN1 = 2048, CN2 = 8192, CK = 33;
constexpr int CIN = 256, CHID = 128, CNH = 8;

using u16    = unsigned short;
using f32x4  = __attribute__((ext_vector_type(4))) float;
using bf16x8 = __attribute__((ext_vector_type(8))) short;

__device__ __forceinline__ u16 f2bf(float f) {
    unsigned u = __float_as_uint(f);
    u += 0x7fff + ((u >> 16) & 1);   // RNE
    return (u16)(u >> 16);
}
__device__ __forceinline__ float bf2f(u16 h) {
    return __uint_as_float(((unsigned)h) << 16);
}

#define GLD16(g, l)                                                        \
    __builtin_amdgcn_global_load_lds(                                      \
        (const __attribute__((address_space(1))) void*)(g),                \
        (__attribute__((address_space(3))) void*)(l), 16, 0, 0)

// ---------------------------------------------------------------------------
// prep2: W1/W2 transpose-convert + pvec = W1_h @ a1 halves.
// blocks [0,256): W1 T; [256,384): W2 T; [384,400): pvec
// ---------------------------------------------------------------------------
__global__ __launch_bounds__(256) void prep2_k(const float* __restrict__ W1,
                                               u16* __restrict__ w1t,
                                               const float* __restrict__ W2,
                                               u16* __restrict__ w2t,
                                               const float* __restrict__ a1,
                                               float* __restrict__ pvec) {
    __shared__ float t[32][33];
    int b = blockIdx.x;
    if (b >= 384) {   // pvec: 16 blocks, one per (head, half)
        const int i = b - 384;
        const int h = i >> 1, half = i & 1;
        const int j = threadIdx.x;   // 0..255
        const float* wrow = W1 + (size_t)h * CIN * CHID + (size_t)j * CHID;
        const float* ah   = a1 + h * 2 * CHID + half * CHID;
        float d = 0.f;
#pragma unroll 8
        for (int c = 0; c < CHID; ++c) d = fmaf(wrow[c], ah[c], d);
        pvec[(h * 2 + half) * CIN + j] = d;
        return;
    }
    const float* ip;
    u16* op;
    int R, C, r0, c0;
    if (b < 256) {  // W1 head h
        const int h = b >> 5, w = b & 31;
        ip = W1 + (size_t)h * CIN * CHID;
        op = w1t + (size_t)h * CIN * CHID;
        R = CIN; C = CHID; r0 = (w >> 2) * 32; c0 = (w & 3) * 32;
    } else {        // W2
        b -= 256;
        ip = W2; op = w2t;
        R = CNH * CHID; C = CHID; r0 = (b >> 2) * 32; c0 = (b & 3) * 32;
    }
    const int tx = threadIdx.x & 31, ty = threadIdx.x >> 5;
#pragma unroll
    for (int i = 0; i < 4; ++i)
        t[ty + 8 * i][tx] = ip[(size_t)(r0 + ty + 8 * i) * C + c0 + tx];
    __syncthreads();
#pragma unroll
    for (int i = 0; i < 4; ++i)
        op[(size_t)(c0 + ty + 8 * i) * R + r0 + tx] = f2bf(t[tx][ty + 8 * i]);
}

// ---------------------------------------------------------------------------
// fsc: feats f32 -> fb bf16 AND all-head scores in one pass.
// one wave per node (4 nodes / 256-thread block).
// ---------------------------------------------------------------------------
__global__ __launch_bounds__(256) void fsc_k(const float* __restrict__ feats,
                                             u16* __restrict__ fb,
                                             const float* __restrict__ pvec,
                                             float* __restrict__ s1,
                                             float* __restrict__ s2) {
    const int node = (blockIdx.x * 256 + threadIdx.x) >> 6;
    const int lane = threadIdx.x & 63;
    const float4 v = *reinterpret_cast<const float4*>(feats + (size_t)node * CIN + lane * 4);
    *reinterpret_cast<ushort4*>(fb + (size_t)node * CIN + lane * 4) =
        make_ushort4(f2bf(v.x), f2bf(v.y), f2bf(v.z), f2bf(v.w));
#pragma unroll
    for (int h = 0; h < CNH; ++h) {
        const float4 p1 = *reinterpret_cast<const float4*>(pvec + (h * 2 + 0) * CIN + lane * 4);
        const float4 p2 = *reinterpret_cast<const float4*>(pvec + (h * 2 + 1) * CIN + lane * 4);
        float d1 = v.x * p1.x + v.y * p1.y + v.z * p1.z + v.w * p1.w;
        float d2 = v.x * p2.x + v.y * p2.y + v.z * p2.z + v.w * p2.w;
#pragma unroll
        for (int m = 1; m < 64; m <<= 1) {
            d1 += __shfl_xor(d1, m);
            d2 += __shfl_xor(d2, m);
        }
        if (lane == 0) {
            s1[h * CN2 + node] = d1;
            s2[h * CN2 + node] = d2;
        }
    }
}

// ---------------------------------------------------------------------------
// layer-1 softmax + feats-gather-aggregate -> g[h][t][c] bf16.
// One 128-thread block per target.
// ---------------------------------------------------------------------------
__global__ __launch_bounds__(128) void agg1g_k(const float* __restrict__ s1,
                                               const float* __restrict__ s2,
                                               const int* __restrict__ src,
                                               const int* __restrict__ dst,
                                               const u16* __restrict__ fb,
                                               u16* __restrict__ gb) {
    __shared__ float wgt[CNH][CK];
    __shared__ int dsts[CK];

    const int t    = blockIdx.x;
    const int tid  = threadIdx.x;
    const int wv   = tid >> 6;
    const int lane = tid & 63;

    int sv = 0, dv = 0;
    if (lane < CK) {
        sv = src[t * CK + lane];
        dv = dst[t * CK + lane];
        if (tid < CK) dsts[tid] = dv;
    }
#pragma unroll
    for (int hh = 0; hh < 4; ++hh) {
        const int head = wv * 4 + hh;
        float e = -3.0e38f;
        if (lane < CK) {
            const float ee = s1[head * CN2 + sv] + s2[head * CN2 + dv];
            e = (ee > 0.f) ? ee : ALPHA * ee;
        }
        float m = e;
#pragma unroll
        for (int mm = 1; mm < 64; mm <<= 1) m = fmaxf(m, __shfl_xor(m, mm));
        const float p = (lane < CK) ? __expf(e - m) : 0.f;
        float s = p;
#pragma unroll
        for (int mm = 1; mm < 64; mm <<= 1) s += __shfl_xor(s, mm);
        if (lane < CK) wgt[head][lane] = p / s;
    }
    __syncthreads();

    const int c2 = tid * 2;
    float acc[CNH][2];
#pragma unroll
    for (int h = 0; h < CNH; ++h) { acc[h][0] = 0.f; acc[h][1] = 0.f; }
#pragma unroll 4
    for (int k = 0; k < CK; ++k) {
        const unsigned w2 = *reinterpret_cast<const unsigned*>(
            fb + (size_t)dsts[k] * CIN + c2);
        const float f0 = bf2f((u16)(w2 & 0xffff));
        const float f1 = bf2f((u16)(w2 >> 16));
#pragma unroll
        for (int h = 0; h < CNH; ++h) {
            const float wk = wgt[h][k];
            acc[h][0] = fmaf(wk, f0, acc[h][0]);
            acc[h][1] = fmaf(wk, f1, acc[h][1]);
        }
    }
#pragma unroll
    for (int h = 0; h < CNH; ++h) {
        const unsigned o = ((unsigned)f2bf(acc[h][1]) << 16) | f2bf(acc[h][0]);
        *reinterpret_cast<unsigned*>(gb + ((size_t)h * CN1 + t) * CIN + c2) = o;
    }
}

// ---------------------------------------------------------------------------
// fused projection + layer-2 partial GEMM.
// Block (trow, h): x = ELU(g_h[64 rows] @ W1_h)  [64x128, via MFMA, dbuf LDS]
//                  -> Xs (bf16, XOR-chunk-swizzled LDS, aliases staging bufs)
//                  -> part[h] = Xs @ W2_h        [64x128, B-frags from L2]
// part[h][t][c] then reduced over h by scores2_k (h == split index).
// ---------------------------------------------------------------------------
__global__ __launch_bounds__(256) void fusedproj_k(const u16* __restrict__ gb,
                                                   const u16* __restrict__ w1t,
                                                   const u16* __restrict__ w2t,
                                                   float* __restrict__ part) {
    __shared__ __attribute__((aligned(16))) char smem[24576];

    const int tid  = threadIdx.x;
    const int lane = tid & 63;
    const int wave = tid >> 6;
    const int trow0 = blockIdx.x * 64;
    const int h     = blockIdx.y;
    const int wr = (wave >> 1) * 32;   // 0 / 32
    const int wc = (wave & 1) * 64;    // 0 / 64

    const u16* A  = gb  + (size_t)h * CN1 * CIN;    // [2048][256]
    const u16* Bt = w1t + (size_t)h * CHID * CIN;   // [128][256]

    f32x4 acc[2][4];
#pragma unroll
    for (int m = 0; m < 2; ++m)
#pragma unroll
        for (int n = 0; n < 4; ++n) acc[m][n] = (f32x4){0.f, 0.f, 0.f, 0.f};

    // ---- GEMM1: staging (round-7-proven 64x128 structure) ----
    const int r0c = tid >> 2;
    const int cs0 = tid & 3;
    const int c0  = (cs0 - (r0c >> 1)) & 3;
    const int r1c = r0c + 64;

    const u16* ga0 = A + (size_t)(trow0 + r0c) * CIN + c0 * 8;
    const u16* gb0 = Bt + (size_t)r0c * CIN + c0 * 8;
    const u16* gb1 = Bt + (size_t)r1c * CIN + c0 * 8;

    auto STAGE = [&](int s) {
        const int k0 = s * 32;
        char* base = smem + (s & 1) * 12288;
        u16* as = (u16*)base + wave * 512;
        u16* bs = (u16*)(base + 4096) + wave * 512;
        GLD16(ga0 + k0, as);
        GLD16(gb0 + k0, bs);
        GLD16(gb1 + k0, bs + 2048);
    };

    STAGE(0);
    __syncthreads();

    for (int s = 0; s < 8; ++s) {
        if (s + 1 < 8) STAGE(s + 1);

        const u16* Acur = (const u16*)(smem + (s & 1) * 12288);
        const u16* Bcur = Acur + 2048;

        bf16x8 af[2], bfr[4];
#pragma unroll
        for (int m = 0; m < 2; ++m) {
            const int rt = wr + m * 16 + (lane & 15);
            const int cs = ((lane >> 4) + (rt >> 1)) & 3;
            af[m] = *reinterpret_cast<const bf16x8*>(Acur + rt * 32 + cs * 8);
        }
#pragma unroll
        for (int n = 0; n < 4; ++n) {
            const int rt2 = wc + n * 16 + (lane & 15);
            const int cs2 = ((lane >> 4) + (rt2 >> 1)) & 3;
            bfr[n] = *reinterpret_cast<const bf16x8*>(Bcur + rt2 * 32 + cs2 * 8);
        }
#pragma unroll
        for (int m = 0; m < 2; ++m)
#pragma unroll
            for (int n = 0; n < 4; ++n)
                acc[m][n] = __builtin_amdgcn_mfma_f32_16x16x32_bf16(
                    af[m], bfr[n], acc[m][n], 0, 0, 0);

        __syncthreads();
    }

    // ---- ELU -> bf16 -> Xs (XOR-chunk swizzle: chunk c of row r at c^(r&7)) ----
    u16* Xs = (u16*)smem;   // 64x128 u16 = 16KB, aliases dead staging bufs
#pragma unroll
    for (int m = 0; m < 2; ++m) {
        const int rr = wr + m * 16 + (lane >> 4) * 4;
#pragma unroll
        for (int n = 0; n < 4; ++n) {
            const int cc = wc + n * 16 + (lane & 15);
#pragma unroll
            for (int q = 0; q < 4; ++q) {
                float v = acc[m][n][q];
                v = (v > 0.f) ? v : __expf(v) - 1.f;   // ELU
                const int r = rr + q;
                Xs[r * 128 + ((((cc >> 3) ^ (r & 7)) << 3) | (cc & 7))] = f2bf(v);
            }
        }
    }
    __syncthreads();

    // ---- GEMM2: part[h] = Xs @ W2_h (K=128, 4 steps; no barriers) ----
    f32x4 acc2[2][4];
#pragma unroll
    for (int m = 0; m < 2; ++m)
#pragma unroll
        for (int n = 0; n < 4; ++n) acc2[m][n] = (f32x4){0.f, 0.f, 0.f, 0.f};

#pragma unroll
    for (int ks = 0; ks < 4; ++ks) {
        bf16x8 a2f[2], b2f[4];
#pragma unroll
        for (int m = 0; m < 2; ++m) {
            const int rt = wr + m * 16 + (lane & 15);
            const int k0 = ks * 32 + (lane >> 4) * 8;
            a2f[m] = *reinterpret_cast<const bf16x8*>(
                Xs + rt * 128 + (((k0 >> 3) ^ (rt & 7)) << 3));
        }
#pragma unroll
        for (int n = 0; n < 4; ++n) {
            const int rb = wc + n * 16 + (lane & 15);   // output col
            b2f[n] = *reinterpret_cast<const bf16x8*>(
                w2t + (size_t)rb * (CNH * CHID) + h * CHID + ks * 32 + (lane >> 4) * 8);
        }
#pragma unroll
        for (int m = 0; m < 2; ++m)
#pragma unroll
            for (int n = 0; n < 4; ++n)
                acc2[m][n] = __builtin_amdgcn_mfma_f32_16x16x32_bf16(
                    a2f[m], b2f[n], acc2[m][n], 0, 0, 0);
    }

    // write part[h][trow0+r][c]  (C/D layout m89)
#pragma unroll
    for (int m = 0; m < 2; ++m) {
        const int rr = trow0 + wr + m * 16 + (lane >> 4) * 4;
#pragma unroll
        for (int n = 0; n < 4; ++n) {
            const int cc = wc + n * 16 + (lane & 15);
#pragma unroll
            for (int q = 0; q < 4; ++q)
                part[((size_t)h * CN1 + rr + q) * CHID + cc] = acc2[m][n][q];
        }
    }
}

// ---------------------------------------------------------------------------
// layer-2: reduce 8 head-partials -> h2 f32, + scores. one wave per node
// ---------------------------------------------------------------------------
__global__ __launch_bounds__(256) void scores2_k(const float* __restrict__ part,
                                                 const float* __restrict__ a,
                                                 float* __restrict__ h2,
                                                 float* __restrict__ s1,
                                                 float* __restrict__ s2) {
    const int wid  = (blockIdx.x * 256 + threadIdx.x) >> 6;   // node
    const int lane = threadIdx.x & 63;
    const int j = lane * 2;
    float x0 = 0.f, x1 = 0.f;
#pragma unroll
    for (int sp = 0; sp < 8; ++sp) {
        const float2 v = *reinterpret_cast<const float2*>(
            part + (size_t)sp * CN1 * CHID + (size_t)wid * CHID + j);
        x0 += v.x; x1 += v.y;
    }
    *reinterpret_cast<float2*>(h2 + (size_t)wid * CHID + j) = make_float2(x0, x1);
    float d1 = x0 * a[j] + x1 * a[j + 1];
    float d2 = x0 * a[CHID + j] + x1 * a[CHID + j + 1];
#pragma unroll
    for (int m = 1; m < 64; m <<= 1) {
        d1 += __shfl_xor(d1, m);
        d2 += __shfl_xor(d2, m);
    }
    if (lane == 0) { s1[wid] = d1; s2[wid] = d2; }
}

// ---------------------------------------------------------------------------
// layer-2 softmax+aggregate+ELU: one wave per target; f32 in/out
// ---------------------------------------------------------------------------
__global__ __launch_bounds__(256) void agg2_k(const float* __restrict__ s1,
                                              const float* __restrict__ s2,
                                              const int* __restrict__ src,
                                              const int* __restrict__ dst,
                                              const float* __restrict__ h2,
                                              float* __restrict__ out) {
    const int t    = (blockIdx.x * 256 + threadIdx.x) >> 6;
    const int lane = threadIdx.x & 63;

    float e = -3.0e38f;
    int dv = 0;
    if (lane < CK) {
        const int sv = src[t * CK + lane];
        dv = dst[t * CK + lane];
        const float ee = s1[sv] + s2[dv];
        e = (ee > 0.f) ? ee : ALPHA * ee;
    }
    float m = e;
#pragma unroll
    for (int mm = 1; mm < 64; mm <<= 1) m = fmaxf(m, __shfl_xor(m, mm));
    float p = (lane < CK) ? __expf(e - m) : 0.f;
    float ssum = p;
#pragma unroll
    for (int mm = 1; mm < 64; mm <<= 1) ssum += __shfl_xor(ssum, mm);
    const float invs = 1.f / ssum;

    float a0 = 0.f, a1 = 0.f;
#pragma unroll
    for (int k = 0; k < CK; ++k) {
        const float w = __shfl(p, k) * invs;
        const int d = __shfl(dv, k);
        const float2 hv = *reinterpret_cast<const float2*>(h2 + (size_t)d * CHID + lane * 2);
        a0 = fmaf(w, hv.x, a0);
        a1 = fmaf(w, hv.y, a1);
    }
    a0 = (a0 > 0.f) ? a0 : __expf(a0) - 1.f;
    a1 = (a1 > 0.f) ? a1 : __expf(a1) - 1.f;
    *reinterpret_cast<float2*>(out + (size_t)t * CHID + lane * 2) = make_float2(a0, a1);
}

// ---------------------------------------------------------------------------
extern "C" void kernel_launch(void* const* d_in, const int* in_sizes, int n_in,
                              void* d_out, int out_size, void* d_ws, size_t ws_size,
                              hipStream_t stream) {
    const float* feats = (const float*)d_in[0];
    const float* W1    = (const float*)d_in[1];
    const float* a1    = (const float*)d_in[2];
    const float* W2    = (const float*)d_in[3];
    const float* a2    = (const float*)d_in[4];
    const int*   src1  = (const int*)d_in[5];
    const int*   dst1  = (const int*)d_in[6];
    const int*   src2  = (const int*)d_in[8];
    const int*   dst2  = (const int*)d_in[9];
    float* out = (float*)d_out;

    char* w = (char*)d_ws;
    u16*   fb   = (u16*)w;                 w += (size_t)CN2 * CIN * 2;          // 4 MB
    u16*   w1t  = (u16*)w;                 w += (size_t)CNH * CIN * CHID * 2;
    u16*   w2t  = (u16*)w;                 w += (size_t)CNH * CHID * CHID * 2;
    float* pvec = (float*)w;               w += (size_t)CNH * 2 * CIN * 4;      // 16 KB
    float* s1   = (float*)w;               w += (size_t)CNH * CN2 * 4;
    float* s2   = (float*)w;               w += (size_t)CNH * CN2 * 4;
    u16*   gb   = (u16*)w;                 w += (size_t)CNH * CN1 * CIN * 2;    // 8 MB
    float* part = (float*)w;               w += (size_t)8 * CN1 * CHID * 4;     // 8 MB
    float* h2   = (float*)w;               w += (size_t)CN1 * CHID * 4;
    float* s21  = (float*)w;               w += (size_t)CN1 * 4;
    float* s22  = (float*)w;               w += (size_t)CN1 * 4;

    // ---- prep: W transposes + pvec ----
    prep2_k<<<dim3(256 + 128 + 16), 256, 0, stream>>>(W1, w1t, W2, w2t, a1, pvec);

    // ---- feats convert + all-head layer-1 scores (fused) ----
    fsc_k<<<dim3(CN2 / 4), 256, 0, stream>>>(feats, fb, pvec, s1, s2);

    // ---- layer-1 softmax + feats-aggregate -> g [8][2048][256] bf16 ----
    agg1g_k<<<dim3(CN1), 128, 0, stream>>>(s1, s2, src1, dst1, fb, gb);

    // ---- fused: x_h = ELU(g_h @ W1_h); part[h] = x_h @ W2_h ----
    fusedproj_k<<<dim3(CN1 / 64, CNH), 256, 0, stream>>>(gb, w1t, w2t, part);

    // ---- reduce partials -> h2 + layer-2 scores ----
    scores2_k<<<dim3(CN1 / 4), 256, 0, stream>>>(part, a2, h2, s21, s22);

    // ---- layer-2 softmax + aggregate + ELU ----
    agg2_k<<<dim3(CN0 / 4), 256, 0, stream>>>(s21, s22, src2, dst2, h2, out);
}